// Round 11
// baseline (300.734 us; speedup 1.0000x reference)
//
#include <hip/hip_runtime.h>
#include <stdint.h>

// NNCLR forward on MI355X — round 16.
// Changes vs round 15 (214.1 us, flat/inconclusive):
//  * k2_mfma: 4 -> 3 LDS buffers (64 -> 48 KB) -> 3 blocks/CU via __launch_bounds__(256,3).
//    Depth-2 pipeline only needs 3 live buffers (read h / staged h+1 / filling h+2);
//    end-barrier already protects reuse. Instruction sequence identical -> r13-verified
//    vmcnt counts stay valid. +50% waves/CU for latency hiding.
//  * k01_prep (k0 part): r15 conflated MLP with occupancy (16 live f32x4 ~100 VGPR cut
//    waves/SIMD 8->5). Revert to 32-row slabs (grid 2048, 8 waves/SIMD) but with EIGHT
//    NAMED f32x4 (no array -> no load-sinking). Clean MLP-at-constant-TLP test:
//    VGPR ~60 + drop => confirmed; flat => k01 is at a mixed-stream wall, final.
//  * k2cd / k3 / k4 byte-identical (passed, absmax 0).

#define BATCH  512
#define DIM    256
#define QUEUE  65536
#define MROWS  1024
#define NGRP   2048          // 65536 / 32
#define MARGIN 0.01f

typedef short bf16x8 __attribute__((ext_vector_type(8)));
typedef float f32x4  __attribute__((ext_vector_type(4)));

__device__ __forceinline__ unsigned int mono_f32(float f) {
    unsigned int u = __float_as_uint(f);
    return (u & 0x80000000u) ? ~u : (u | 0x80000000u);
}
__device__ __forceinline__ float unmono_f32(unsigned int m) {
    unsigned int u = (m & 0x80000000u) ? (m ^ 0x80000000u) : ~m;
    return __uint_as_float(u);
}
__device__ __forceinline__ unsigned short f2bf(float f) {   // RNE fp32->bf16
    unsigned int u = __float_as_uint(f);
    return (unsigned short)((u + 0x7fffu + ((u >> 16) & 1u)) >> 16);
}
__device__ __forceinline__ bf16x8 cvt8(f32x4 a, f32x4 b) {
    bf16x8 r;
    r[0] = (short)f2bf(a.x); r[1] = (short)f2bf(a.y);
    r[2] = (short)f2bf(a.z); r[3] = (short)f2bf(a.w);
    r[4] = (short)f2bf(b.x); r[5] = (short)f2bf(b.y);
    r[6] = (short)f2bf(b.z); r[7] = (short)f2bf(b.w);
    return r;
}

// ---------------- k01: (blocks 0..255) normalize | (256..2303) queue->outq + Qbf ----------
// k0 part: 32-row slab per block. Phase 1: 8 NAMED f32x4 loads (straight-line, pinned by
// sched_barrier; no array so nothing to sink); phase 2: plain outq stores + one 16B Qbf
// store per 32B pair. Qbf tile (b0>>1) at byte (b0>>1)*32768; 16B chunk (rr,c16) at
// rr*512 + ((c16^(rr&31))<<4) — the LDS image k2 reads.
// PhiF 16B-chunk idx for (row r, k-chunk c): ((r>>4)*8+(c>>2))*64+(c&3)*16+(r&15).
__global__ __launch_bounds__(256)
void k01_prep(const float* __restrict__ queue, float* __restrict__ outq,
              char* __restrict__ Qbf,
              const float* __restrict__ p1, const float* __restrict__ p2,
              float* __restrict__ Pn, float* __restrict__ PnT,
              unsigned short* __restrict__ PhiF,
              unsigned int* __restrict__ rowmaxU, unsigned long long* __restrict__ rowfinal)
{
    const int bid = blockIdx.x;
    const int t = threadIdx.x;       // 0..255

    if (bid >= 256) {
        // ---------- k0: FIFO copy + Qbf ----------
        const int b0 = bid - 256;               // 0..2047
        const int n0 = b0 * 32;
        const f32x4* qsrc = (const f32x4*)(queue + (size_t)n0 * DIM);
        f32x4* qdst = (f32x4*)(outq + (size_t)(n0 + BATCH) * DIM);
        char* tile = Qbf + (size_t)(b0 >> 1) * 32768;

        // phase 1: 8 named loads, all issued
        f32x4 B0, B1, B2, B3, B4, B5, B6, B7;
        B0 = qsrc[(size_t)2 * (0 * 256 + t)];  B1 = qsrc[(size_t)2 * (0 * 256 + t) + 1];
        B2 = qsrc[(size_t)2 * (1 * 256 + t)];  B3 = qsrc[(size_t)2 * (1 * 256 + t) + 1];
        B4 = qsrc[(size_t)2 * (2 * 256 + t)];  B5 = qsrc[(size_t)2 * (2 * 256 + t) + 1];
        B6 = qsrc[(size_t)2 * (3 * 256 + t)];  B7 = qsrc[(size_t)2 * (3 * 256 + t) + 1];
        __builtin_amdgcn_sched_barrier(0);     // pin: all 8 loads issued before stores

        // phase 2: stores + convert. pair p: M = p*256+t, r = M>>5, c16 = M&31.
        #define K0_STORE(p, X, Y)                                                   \
        {                                                                           \
            const int M = (p) * 256 + t;                                            \
            const int r = M >> 5, c16 = M & 31;                                     \
            if (n0 + r < QUEUE - BATCH) {                                           \
                qdst[(size_t)2 * M]     = X;                                        \
                qdst[(size_t)2 * M + 1] = Y;                                        \
            }                                                                       \
            const int rr = ((b0 & 1) << 5) + r;                                     \
            *(bf16x8*)(tile + rr * 512 + ((c16 ^ (rr & 31)) << 4)) = cvt8(X, Y);    \
        }
        K0_STORE(0, B0, B1)
        K0_STORE(1, B2, B3)
        K0_STORE(2, B4, B5)
        K0_STORE(3, B6, B7)
        #undef K0_STORE
    } else {
        // ---------- k1: normalize 4 rows (one per wave) ----------
        const int sub = t >> 6, lane = t & 63;
        const int r = bid * 4 + sub;             // 0..1023
        if (lane == 0) {                          // ws re-poisoned 0xAA each call
            rowmaxU[r] = 0u;
            rowfinal[r] = 0ull;
        }
        const float* src = (r < BATCH) ? p1 : p2;
        const int row = (r < BATCH) ? r : r - BATCH;
        float4 v = ((const float4*)(src + (size_t)row * DIM))[lane];
        float sq = v.x*v.x + v.y*v.y + v.z*v.z + v.w*v.w;
        #pragma unroll
        for (int off = 32; off; off >>= 1) sq += __shfl_xor(sq, off, 64);
        sq = fmaxf(sq, 1e-12f);
        float s = rsqrtf(sq);
        s = s * (1.5f - 0.5f * sq * s * s);
        v.x *= s; v.y *= s; v.z *= s; v.w *= s;
        ((float4*)(Pn + (size_t)r * DIM))[lane] = v;
        const int k = lane * 4;
        PnT[(size_t)(k + 0) * MROWS + r] = v.x;
        PnT[(size_t)(k + 1) * MROWS + r] = v.y;
        PnT[(size_t)(k + 2) * MROWS + r] = v.z;
        PnT[(size_t)(k + 3) * MROWS + r] = v.w;
        short4 b;
        b.x = (short)f2bf(v.x); b.y = (short)f2bf(v.y);
        b.z = (short)f2bf(v.z); b.w = (short)f2bf(v.w);
        {
            const int c = lane >> 1;
            const int idx = ((r >> 4) * 8 + (c >> 2)) * 64 + (c & 3) * 16 + (r & 15);
            *(short4*)((char*)PhiF + (size_t)idx * 16 + (lane & 1) * 8) = b;
        }
        if (r < BATCH) ((float4*)(outq + (size_t)r * DIM))[lane] = v;  // new_queue[0:512] = p1n
    }
}

// ---------------- k2: bf16 MFMA GEMM filter, depth-2 counted-vmcnt pipeline ----------------
// Grid 1024; bid remap c=(bid>>5)*8+(bid&7), s=(bid>>3)&3 (XCD sharing of Qbf chunks).
// Block = 256 thr = 4 waves; wave w: m-rows [s*256 + w*64, +64), pfr[4][8] resident.
// 8 half-tiles of 32 rows (16KB) per chunk, THREE LDS buffers (48KB -> 3 blocks/CU).
// Depth-2 only has 3 live: read h%3, staged (h+1)%3, filling (h+2)%3; end-barrier
// protects reuse of h%3 by stage(h+3). Per half h:
//   issue stage(h+2) -> s_waitcnt vmcnt(N) [FIFO-exact] -> s_barrier -> 16 ds_read +
//   64 MFMA + epilogue (4 cand stores) -> s_barrier.
// vmcnt N: h=0:8 [s1,s2]; h=1..5:12 [stores(h-1),s(h+1),s(h+2)]; h=6:8; h=7:4.
__device__ __forceinline__ void k2_stage_half(const char* __restrict__ src,
                                              char* dst, int t)
{
    #pragma unroll
    for (int it = 0; it < 4; ++it) {
        const int L = it * 256 + t;          // 0..1023 chunks of 16B
        __builtin_amdgcn_global_load_lds(
            (const __attribute__((address_space(1))) unsigned int*)(src + (size_t)L * 16),
            (__attribute__((address_space(3))) unsigned int*)(dst + L * 16), 16, 0, 0);
    }
}

__global__ __launch_bounds__(256, 3)
void k2_mfma(const unsigned short* __restrict__ PhiF, const char* __restrict__ Qbf,
             float* __restrict__ cand, unsigned int* __restrict__ rowmaxU)
{
    __shared__ __align__(16) char Bs[3][16384];
    const int bid = blockIdx.x;      // 0..1023
    const int c = (bid >> 5) * 8 + (bid & 7);   // n-chunk 0..255
    const int s = (bid >> 3) & 3;               // m-strip 0..3
    const int t  = threadIdx.x;
    const int w  = t >> 6, lane = t & 63;
    const int lr = lane & 15, q = lane >> 4;
    const int mbase = s * 256 + w * 64;
    const char* chunkbase = Qbf + (size_t)(c * 4) * 32768;   // 8 halves x 16KB

    // ---- preload P fragments: 64 m-rows x K=256 resident; coalesced from PhiF
    bf16x8 pfr[4][8];
    {
        const char* Pw = (const char*)PhiF;
        const int mt16b = mbase >> 4;        // base 16-row tile index
        #pragma unroll
        for (int mj = 0; mj < 4; ++mj)
            #pragma unroll
            for (int ks = 0; ks < 8; ++ks)
                pfr[mj][ks] = *(const bf16x8*)(Pw + ((size_t)((mt16b + mj) * 8 + ks) * 64 + lane) * 16);
    }

    k2_stage_half(chunkbase,         Bs[0], t);
    k2_stage_half(chunkbase + 16384, Bs[1], t);

    float rowmx[4] = {-1e30f, -1e30f, -1e30f, -1e30f};

    #pragma unroll
    for (int h = 0; h < 8; ++h) {
        if (h + 2 < 8)
            k2_stage_half(chunkbase + (size_t)(h + 2) * 16384, Bs[(h + 2) % 3], t);

        // FIFO-exact wait: everything up through stage(h) drained.
        if (h == 0)      asm volatile("s_waitcnt vmcnt(8)"  ::: "memory");
        else if (h <= 5) asm volatile("s_waitcnt vmcnt(12)" ::: "memory");
        else if (h == 6) asm volatile("s_waitcnt vmcnt(8)"  ::: "memory");
        else             asm volatile("s_waitcnt vmcnt(4)"  ::: "memory");
        __builtin_amdgcn_s_barrier();
        __builtin_amdgcn_sched_barrier(0);

        const char* Bsb = Bs[h % 3];
        f32x4 acc[2][4];                 // [ni][mj]
        #pragma unroll
        for (int i = 0; i < 2; ++i)
            #pragma unroll
            for (int j = 0; j < 4; ++j) acc[i][j] = (f32x4){0.f, 0.f, 0.f, 0.f};

        #pragma unroll
        for (int ks = 0; ks < 8; ++ks) {
            bf16x8 qf[2];
            #pragma unroll
            for (int ni = 0; ni < 2; ++ni) {
                const int rl = ni * 16 + lr;            // local row 0..31
                const int c16 = ks * 4 + q;
                qf[ni] = *(const bf16x8*)(Bsb + rl * 512 + ((c16 ^ rl) << 4));
            }
            #pragma unroll
            for (int ni = 0; ni < 2; ++ni)
                #pragma unroll
                for (int mj = 0; mj < 4; ++mj)
                    acc[ni][mj] = __builtin_amdgcn_mfma_f32_16x16x32_bf16(qf[ni], pfr[mj][ks], acc[ni][mj], 0, 0, 0);
        }

        // ---- epilogue: per (m, 32-n-group) max; group = c*8 + h.
        #pragma unroll
        for (int mj = 0; mj < 4; ++mj) {
            f32x4 va = acc[0][mj], vb = acc[1][mj];
            float mx = fmaxf(fmaxf(fmaxf(va[0], va[1]), fmaxf(va[2], va[3])),
                             fmaxf(fmaxf(vb[0], vb[1]), fmaxf(vb[2], vb[3])));
            mx = fmaxf(mx, __shfl_xor(mx, 16, 64));
            mx = fmaxf(mx, __shfl_xor(mx, 32, 64));
            rowmx[mj] = fmaxf(rowmx[mj], mx);
            if (q == 0)
                cand[(size_t)(c * 8 + h) * MROWS + (mbase + mj * 16 + lr)] = mx;
        }
        __builtin_amdgcn_s_barrier();
        __builtin_amdgcn_sched_barrier(0);
    }

    // ---- fused rowmax: one atomic per m per block
    if (q == 0) {
        #pragma unroll
        for (int mj = 0; mj < 4; ++mj)
            atomicMax(rowmaxU + mbase + mj * 16 + lr, mono_f32(rowmx[mj]));
    }
}

// ---------------- k2cd: margin filter -> LDS hit list -> exact fp32 rescore ----------------
// Grid 512 = 16 m-chunks x 32 g-chunks (64 g each). Phase 1: scan cand, push hits to LDS
// (cap 4096 = 64m x 64g max). Phase 2: waves rescore hits round-robin; one wave per
// (row,group): 32 cols x 256-dim fp32 dot, atomicMax(rowfinal).
__global__ __launch_bounds__(256)
void k2cd(const float* __restrict__ cand, const unsigned int* __restrict__ rowmaxU,
          const float* __restrict__ Pn, const float* __restrict__ queue,
          unsigned long long* __restrict__ rowfinal)
{
    __shared__ unsigned int hits[4096];
    __shared__ int nhits;
    const int t = threadIdx.x;               // 256
    if (t == 0) nhits = 0;
    __syncthreads();

    {   // ---- phase 1: filter
        const int ml = t & 63, gs = t >> 6;
        const int mc = blockIdx.x & 15, gc = blockIdx.x >> 4;   // gc 0..31
        const int m  = mc * 64 + ml;
        const int g0 = gc * 64 + gs * 16;
        const float thr = unmono_f32(rowmaxU[m]) - MARGIN;
        #pragma unroll 8
        for (int j = 0; j < 16; ++j) {
            if (cand[(size_t)(g0 + j) * MROWS + m] >= thr) {
                int p = atomicAdd(&nhits, 1);
                hits[p] = ((unsigned int)m << 16) | (unsigned int)(g0 + j);
            }
        }
    }
    __syncthreads();

    // ---- phase 2: rescore
    const int n = nhits;
    const int w = t >> 6, lane = t & 63;
    const int col_l = lane & 31, half = lane >> 5;
    for (int p = w; p < n; p += 4) {
        const unsigned int pr = hits[p];
        const int row = pr >> 16, g = pr & 0xffff;
        const int col = g * 32 + col_l;
        const float4* qp = (const float4*)(queue + (size_t)col * DIM + half * 128);
        const float4* pp = (const float4*)(Pn + (size_t)row * DIM + half * 128);
        float4 sv = {0.f, 0.f, 0.f, 0.f};
        #pragma unroll 8
        for (int j = 0; j < 32; ++j) {
            float4 a = pp[j], b = qp[j];
            sv.x = fmaf(a.x, b.x, sv.x); sv.y = fmaf(a.y, b.y, sv.y);
            sv.z = fmaf(a.z, b.z, sv.z); sv.w = fmaf(a.w, b.w, sv.w);
        }
        float s = (sv.x + sv.y) + (sv.z + sv.w);
        s += __shfl_xor(s, 32, 64);                       // combine k-halves
        unsigned long long best = ((unsigned long long)mono_f32(s) << 32)
                                | (unsigned int)(65535 - col);
        #pragma unroll
        for (int off = 1; off <= 16; off <<= 1) {
            unsigned long long o = __shfl_xor(best, off, 64);
            best = best > o ? best : o;
        }
        if (lane == 0) atomicMax(rowfinal + row, best);
    }
}

// ---------------- k3: S1/S2 similarity matrices (4 rows x 256-col half per block) --------
// grid 512: b>>1 = 4-row block (rows of [nn1;nn2]), b&1 = column half.
__global__ void k3_sim(const unsigned long long* __restrict__ rowfinal,
                       const float* __restrict__ queue,
                       const float* __restrict__ PnT, float* __restrict__ S)
{
    const int b  = blockIdx.x;       // 0..511
    const int rb = (b >> 1) * 4;     // 0..1020 (rows of [nn1;nn2])
    const int ch = b & 1;            // column half
    const int tid = threadIdx.x;     // 256
    const int which = (rb < BATCH) ? 0 : 1;
    const int colbase = which ? 0 : BATCH;    // S1 vs p2 (cols 512..1023), S2 vs p1 (0..511)
    const int col = colbase + ch * 256 + tid;
    __shared__ float nnv[4][DIM];
    #pragma unroll
    for (int j = 0; j < 4; ++j) {
        const int idx = 65535 - (int)(rowfinal[rb + j] & 0xFFFFull);
        nnv[j][tid] = queue[(size_t)idx * DIM + tid];
    }
    __syncthreads();
    float acc[4];
    #pragma unroll
    for (int j = 0; j < 4; ++j) acc[j] = 0.f;
    for (int k4 = 0; k4 < 64; ++k4) {
        float4 nv[4];
        #pragma unroll
        for (int j = 0; j < 4; ++j) nv[j] = ((const float4*)nnv[j])[k4];
        #pragma unroll
        for (int kk = 0; kk < 4; ++kk) {
            const int k = k4 * 4 + kk;
            const float v0 = PnT[(size_t)k * MROWS + col];
            #pragma unroll
            for (int j = 0; j < 4; ++j) {
                const float nj = ((const float*)&nv[j])[kk];
                acc[j] = fmaf(nj, v0, acc[j]);
            }
        }
    }
    const int i0 = rb & (BATCH - 1);
    float* Sout = S + (size_t)which * (BATCH * BATCH);
    #pragma unroll
    for (int j = 0; j < 4; ++j)
        Sout[(size_t)(i0 + j) * BATCH + ch * 256 + tid] = acc[j] * 10.0f;
}

// ---------------- k4: loss ----------------
__global__ void k4_loss(const float* __restrict__ S, float* __restrict__ loss)
{
    const int r = blockIdx.x;        // 0..2047
    const int tid = threadIdx.x;     // 256
    const int grp = r >> 9;
    const int i = r & 511;
    const float* M = S + (size_t)(grp >> 1) * (BATCH * BATCH);
    float x0, x1;
    if (!(grp & 1)) { x0 = M[(size_t)i * BATCH + tid];  x1 = M[(size_t)i * BATCH + tid + 256]; }
    else            { x0 = M[(size_t)tid * BATCH + i];  x1 = M[(size_t)(tid + 256) * BATCH + i]; }
    const float diag = M[(size_t)i * BATCH + i];
    float mx = fmaxf(x0, x1);
    #pragma unroll
    for (int off = 1; off < 64; off <<= 1) mx = fmaxf(mx, __shfl_xor(mx, off, 64));
    __shared__ float redm[4], reds[4];
    if ((tid & 63) == 0) redm[tid >> 6] = mx;
    __syncthreads();
    mx = fmaxf(fmaxf(redm[0], redm[1]), fmaxf(redm[2], redm[3]));
    float e = __expf(x0 - mx) + __expf(x1 - mx);
    #pragma unroll
    for (int off = 1; off < 64; off <<= 1) e += __shfl_xor(e, off, 64);
    if ((tid & 63) == 0) reds[tid >> 6] = e;
    __syncthreads();
    if (tid == 0)
        loss[r] = mx + logf(reds[0] + reds[1] + reds[2] + reds[3]) - diag;
}

// ---------------- launcher ----------------
extern "C" void kernel_launch(void* const* d_in, const int* in_sizes, int n_in,
                              void* d_out, int out_size, void* d_ws, size_t ws_size,
                              hipStream_t stream)
{
    const float* p1    = (const float*)d_in[0];
    const float* p2    = (const float*)d_in[1];
    const float* queue = (const float*)d_in[2];
    float* out  = (float*)d_out;
    float* loss = out;
    float* outq = out + 4 * BATCH;

    // Workspace (~44.5 MB)
    char* w = (char*)d_ws;
    float* cand = (float*)w;                               w += (size_t)NGRP * MROWS * 4;   // 8 MB [g][m]
    unsigned long long* rowfinal = (unsigned long long*)w; w += MROWS * 8;
    unsigned int* rowmaxU = (unsigned int*)w;              w += MROWS * 4;
    float* Pn  = (float*)w;                                w += (size_t)MROWS * DIM * 4;    // 1 MB
    float* PnT = (float*)w;                                w += (size_t)MROWS * DIM * 4;    // 1 MB
    unsigned short* PhiF = (unsigned short*)w;             w += (size_t)MROWS * DIM * 2;    // 0.5 MB
    float* S = (float*)w;                                  w += (size_t)2 * BATCH * BATCH * 4; // 2 MB
    char* Qbf = w;                                         // 32 MB (QUEUE*DIM*2)

    hipLaunchKernelGGL(k01_prep,    dim3(256 + 2048), dim3(256), 0, stream,
                       queue, outq, Qbf, p1, p2, Pn, PnT, PhiF, rowmaxU, rowfinal);
    hipLaunchKernelGGL(k2_mfma,     dim3(1024), dim3(256), 0, stream, PhiF, Qbf, cand, rowmaxU);
    hipLaunchKernelGGL(k2cd,        dim3(512),  dim3(256), 0, stream, cand, rowmaxU, Pn, queue, rowfinal);
    hipLaunchKernelGGL(k3_sim,      dim3(512),  dim3(256), 0, stream, rowfinal, queue, PnT, S);
    hipLaunchKernelGGL(k4_loss,     dim3(4 * BATCH), dim3(256), 0, stream, S, loss);
}

// Round 12
// 211.677 us; speedup vs baseline: 1.4207x; 1.4207x over previous
//
#include <hip/hip_runtime.h>
#include <stdint.h>

// NNCLR forward on MI355X — round 17.
// Changes vs round 16 (300.7 us — REGRESSION):
//  * k2_mfma: REVERTED to round-14 form (4 LDS buffers 64KB, launch_bounds(256,2), &3
//    indexing). r16's 3-buffer/(256,3) made regalloc spill pfr: VGPR_Count=84 (<128
//    needed), WRITE_SIZE 113 MB / FETCH 130 MB of scratch traffic, 120 us. Round-8
//    pathology repeated; 4-buffer form is the verified-no-spill one.
//  * outq FIFO copy MOVED OUT of k01 (it was 128 MB of BW work inside a BW-bound kernel,
//    yet nothing downstream reads outq). Copy now rides as hetero-grid appendages on the
//    latency-bound kernels: k2cd blocks 512..1535 copy rows 0..32767, k3 blocks 512..1535
//    copy rows 32768..65023 (guarded). Copy overlaps rescore/dot latency ~free.
//  * k01 k0-part: queue-read + Qbf-write only (96 MB, 8 loads + 4 swizzled 16B stores
//    per thread, r14 array form).
//  * k4 unchanged (passed, absmax 0).

#define BATCH  512
#define DIM    256
#define QUEUE  65536
#define MROWS  1024
#define NGRP   2048          // 65536 / 32
#define MARGIN 0.01f

typedef short bf16x8 __attribute__((ext_vector_type(8)));
typedef float f32x4  __attribute__((ext_vector_type(4)));

__device__ __forceinline__ unsigned int mono_f32(float f) {
    unsigned int u = __float_as_uint(f);
    return (u & 0x80000000u) ? ~u : (u | 0x80000000u);
}
__device__ __forceinline__ float unmono_f32(unsigned int m) {
    unsigned int u = (m & 0x80000000u) ? (m ^ 0x80000000u) : ~m;
    return __uint_as_float(u);
}
__device__ __forceinline__ unsigned short f2bf(float f) {   // RNE fp32->bf16
    unsigned int u = __float_as_uint(f);
    return (unsigned short)((u + 0x7fffu + ((u >> 16) & 1u)) >> 16);
}
__device__ __forceinline__ bf16x8 cvt8(f32x4 a, f32x4 b) {
    bf16x8 r;
    r[0] = (short)f2bf(a.x); r[1] = (short)f2bf(a.y);
    r[2] = (short)f2bf(a.z); r[3] = (short)f2bf(a.w);
    r[4] = (short)f2bf(b.x); r[5] = (short)f2bf(b.y);
    r[6] = (short)f2bf(b.z); r[7] = (short)f2bf(b.w);
    return r;
}

// ---------------- k01: (blocks 0..255) normalize | (256..2303) queue -> Qbf ----------
// k0 part: 32-row slab per block, Qbf ONLY (outq copy moved to k2cd/k3). 8 f32x4 loads,
// 4 swizzled 16B bf16 stores per thread. Qbf tile (b0>>1) at byte (b0>>1)*32768; 16B
// chunk (rr,c16) at rr*512 + ((c16^(rr&31))<<4) — the LDS image k2 reads.
// PhiF 16B-chunk idx for (row r, k-chunk c): ((r>>4)*8+(c>>2))*64+(c&3)*16+(r&15).
__global__ __launch_bounds__(256)
void k01_prep(const float* __restrict__ queue, char* __restrict__ Qbf,
              const float* __restrict__ p1, const float* __restrict__ p2,
              float* __restrict__ Pn, float* __restrict__ PnT,
              unsigned short* __restrict__ PhiF, float* __restrict__ outq,
              unsigned int* __restrict__ rowmaxU, unsigned long long* __restrict__ rowfinal)
{
    const int bid = blockIdx.x;
    const int t = threadIdx.x;       // 0..255

    if (bid >= 256) {
        // ---------- k0: Qbf production ----------
        const int b0 = bid - 256;               // 0..2047
        const int n0 = b0 * 32;
        const f32x4* qsrc = (const f32x4*)(queue + (size_t)n0 * DIM);
        char* tile = Qbf + (size_t)(b0 >> 1) * 32768;

        f32x4 va[8];
        #pragma unroll
        for (int it = 0; it < 4; ++it) {
            const int L = it * 256 + t;          // 0..1023: 32B pair id
            va[2 * it]     = qsrc[(size_t)2 * L];
            va[2 * it + 1] = qsrc[(size_t)2 * L + 1];
        }
        #pragma unroll
        for (int it = 0; it < 4; ++it) {
            const int L = it * 256 + t;
            const int r = L >> 5, c16 = L & 31;
            const int rr = ((b0 & 1) << 5) + r;   // row within 64-row tile
            *(bf16x8*)(tile + rr * 512 + ((c16 ^ (rr & 31)) << 4)) = cvt8(va[2 * it], va[2 * it + 1]);
        }
    } else {
        // ---------- k1: normalize 4 rows (one per wave) ----------
        const int sub = t >> 6, lane = t & 63;
        const int r = bid * 4 + sub;             // 0..1023
        if (lane == 0) {                          // ws re-poisoned 0xAA each call
            rowmaxU[r] = 0u;
            rowfinal[r] = 0ull;
        }
        const float* src = (r < BATCH) ? p1 : p2;
        const int row = (r < BATCH) ? r : r - BATCH;
        float4 v = ((const float4*)(src + (size_t)row * DIM))[lane];
        float sq = v.x*v.x + v.y*v.y + v.z*v.z + v.w*v.w;
        #pragma unroll
        for (int off = 32; off; off >>= 1) sq += __shfl_xor(sq, off, 64);
        sq = fmaxf(sq, 1e-12f);
        float s = rsqrtf(sq);
        s = s * (1.5f - 0.5f * sq * s * s);
        v.x *= s; v.y *= s; v.z *= s; v.w *= s;
        ((float4*)(Pn + (size_t)r * DIM))[lane] = v;
        const int k = lane * 4;
        PnT[(size_t)(k + 0) * MROWS + r] = v.x;
        PnT[(size_t)(k + 1) * MROWS + r] = v.y;
        PnT[(size_t)(k + 2) * MROWS + r] = v.z;
        PnT[(size_t)(k + 3) * MROWS + r] = v.w;
        short4 b;
        b.x = (short)f2bf(v.x); b.y = (short)f2bf(v.y);
        b.z = (short)f2bf(v.z); b.w = (short)f2bf(v.w);
        {
            const int c = lane >> 1;
            const int idx = ((r >> 4) * 8 + (c >> 2)) * 64 + (c & 3) * 16 + (r & 15);
            *(short4*)((char*)PhiF + (size_t)idx * 16 + (lane & 1) * 8) = b;
        }
        if (r < BATCH) ((float4*)(outq + (size_t)r * DIM))[lane] = v;  // new_queue[0:512] = p1n
    }
}

// ---------------- k2: bf16 MFMA GEMM filter, depth-2 counted-vmcnt pipeline ----------------
// ROUND-14 FORM (verified no-spill). Grid 1024; bid remap c=(bid>>5)*8+(bid&7),
// s=(bid>>3)&3 (XCD sharing). Block = 4 waves; wave w: m-rows [s*256+w*64,+64),
// pfr[4][8] resident. 8 half-tiles of 32 rows (16KB), 4 LDS buffers. Per half h:
//   issue stage(h+2) -> s_waitcnt vmcnt(N) [FIFO-exact] -> s_barrier -> 16 ds_read +
//   64 MFMA + epilogue (4 cand stores) -> s_barrier.
// vmcnt N: h=0:8; h=1..5:12 (includes 4 cand stores of h-1); h=6:8; h=7:4.
__device__ __forceinline__ void k2_stage_half(const char* __restrict__ src,
                                              char* dst, int t)
{
    #pragma unroll
    for (int it = 0; it < 4; ++it) {
        const int L = it * 256 + t;          // 0..1023 chunks of 16B
        __builtin_amdgcn_global_load_lds(
            (const __attribute__((address_space(1))) unsigned int*)(src + (size_t)L * 16),
            (__attribute__((address_space(3))) unsigned int*)(dst + L * 16), 16, 0, 0);
    }
}

__global__ __launch_bounds__(256, 2)
void k2_mfma(const unsigned short* __restrict__ PhiF, const char* __restrict__ Qbf,
             float* __restrict__ cand, unsigned int* __restrict__ rowmaxU)
{
    __shared__ __align__(16) char Bs[4][16384];
    const int bid = blockIdx.x;      // 0..1023
    const int c = (bid >> 5) * 8 + (bid & 7);   // n-chunk 0..255
    const int s = (bid >> 3) & 3;               // m-strip 0..3
    const int t  = threadIdx.x;
    const int w  = t >> 6, lane = t & 63;
    const int lr = lane & 15, q = lane >> 4;
    const int mbase = s * 256 + w * 64;
    const char* chunkbase = Qbf + (size_t)(c * 4) * 32768;   // 8 halves x 16KB

    // ---- preload P fragments: 64 m-rows x K=256 resident; coalesced from PhiF
    bf16x8 pfr[4][8];
    {
        const char* Pw = (const char*)PhiF;
        const int mt16b = mbase >> 4;        // base 16-row tile index
        #pragma unroll
        for (int mj = 0; mj < 4; ++mj)
            #pragma unroll
            for (int ks = 0; ks < 8; ++ks)
                pfr[mj][ks] = *(const bf16x8*)(Pw + ((size_t)((mt16b + mj) * 8 + ks) * 64 + lane) * 16);
    }

    k2_stage_half(chunkbase,         Bs[0], t);
    k2_stage_half(chunkbase + 16384, Bs[1], t);

    float rowmx[4] = {-1e30f, -1e30f, -1e30f, -1e30f};

    #pragma unroll
    for (int h = 0; h < 8; ++h) {
        if (h + 2 < 8)
            k2_stage_half(chunkbase + (size_t)(h + 2) * 16384, Bs[(h + 2) & 3], t);

        // FIFO-exact wait: everything up through stage(h) drained.
        if (h == 0)      asm volatile("s_waitcnt vmcnt(8)"  ::: "memory");
        else if (h <= 5) asm volatile("s_waitcnt vmcnt(12)" ::: "memory");
        else if (h == 6) asm volatile("s_waitcnt vmcnt(8)"  ::: "memory");
        else             asm volatile("s_waitcnt vmcnt(4)"  ::: "memory");
        __builtin_amdgcn_s_barrier();
        __builtin_amdgcn_sched_barrier(0);

        const char* Bsb = Bs[h & 3];
        f32x4 acc[2][4];                 // [ni][mj]
        #pragma unroll
        for (int i = 0; i < 2; ++i)
            #pragma unroll
            for (int j = 0; j < 4; ++j) acc[i][j] = (f32x4){0.f, 0.f, 0.f, 0.f};

        #pragma unroll
        for (int ks = 0; ks < 8; ++ks) {
            bf16x8 qf[2];
            #pragma unroll
            for (int ni = 0; ni < 2; ++ni) {
                const int rl = ni * 16 + lr;            // local row 0..31
                const int c16 = ks * 4 + q;
                qf[ni] = *(const bf16x8*)(Bsb + rl * 512 + ((c16 ^ rl) << 4));
            }
            #pragma unroll
            for (int ni = 0; ni < 2; ++ni)
                #pragma unroll
                for (int mj = 0; mj < 4; ++mj)
                    acc[ni][mj] = __builtin_amdgcn_mfma_f32_16x16x32_bf16(qf[ni], pfr[mj][ks], acc[ni][mj], 0, 0, 0);
        }

        // ---- epilogue: per (m, 32-n-group) max; group = c*8 + h.
        #pragma unroll
        for (int mj = 0; mj < 4; ++mj) {
            f32x4 va = acc[0][mj], vb = acc[1][mj];
            float mx = fmaxf(fmaxf(fmaxf(va[0], va[1]), fmaxf(va[2], va[3])),
                             fmaxf(fmaxf(vb[0], vb[1]), fmaxf(vb[2], vb[3])));
            mx = fmaxf(mx, __shfl_xor(mx, 16, 64));
            mx = fmaxf(mx, __shfl_xor(mx, 32, 64));
            rowmx[mj] = fmaxf(rowmx[mj], mx);
            if (q == 0)
                cand[(size_t)(c * 8 + h) * MROWS + (mbase + mj * 16 + lr)] = mx;
        }
        __builtin_amdgcn_s_barrier();
        __builtin_amdgcn_sched_barrier(0);
    }

    // ---- fused rowmax: one atomic per m per block
    if (q == 0) {
        #pragma unroll
        for (int mj = 0; mj < 4; ++mj)
            atomicMax(rowmaxU + mbase + mj * 16 + lr, mono_f32(rowmx[mj]));
    }
}

// ---------------- k2cd: filter+rescore (blocks 0..511) | FIFO copy A (512..1535) ----------
// Filter: 16 m-chunks x 32 g-chunks, LDS hit list (cap 4096), waves rescore round-robin.
// Copy A: queue rows [0, 32768) -> outq rows [512, 33280). No guard needed (all < 65024).
__global__ __launch_bounds__(256)
void k2cd(const float* __restrict__ cand, const unsigned int* __restrict__ rowmaxU,
          const float* __restrict__ Pn, const float* __restrict__ queue,
          unsigned long long* __restrict__ rowfinal, float* __restrict__ outq)
{
    const int bid = blockIdx.x;
    const int t = threadIdx.x;               // 256

    if (bid >= 512) {
        // ---- FIFO copy part A
        const int b0 = bid - 512;            // 0..1023
        const int n0 = b0 * 32;
        const f32x4* qsrc = (const f32x4*)(queue + (size_t)n0 * DIM);
        f32x4* qdst = (f32x4*)(outq + (size_t)(n0 + BATCH) * DIM);
        #pragma unroll
        for (int it = 0; it < 8; ++it) {
            const int idx = it * 256 + t;    // 0..2047
            qdst[idx] = qsrc[idx];
        }
        return;
    }

    __shared__ unsigned int hits[4096];
    __shared__ int nhits;
    if (t == 0) nhits = 0;
    __syncthreads();

    {   // ---- phase 1: filter
        const int ml = t & 63, gs = t >> 6;
        const int mc = bid & 15, gc = bid >> 4;   // gc 0..31
        const int m  = mc * 64 + ml;
        const int g0 = gc * 64 + gs * 16;
        const float thr = unmono_f32(rowmaxU[m]) - MARGIN;
        #pragma unroll 8
        for (int j = 0; j < 16; ++j) {
            if (cand[(size_t)(g0 + j) * MROWS + m] >= thr) {
                int p = atomicAdd(&nhits, 1);
                hits[p] = ((unsigned int)m << 16) | (unsigned int)(g0 + j);
            }
        }
    }
    __syncthreads();

    // ---- phase 2: rescore
    const int n = nhits;
    const int w = t >> 6, lane = t & 63;
    const int col_l = lane & 31, half = lane >> 5;
    for (int p = w; p < n; p += 4) {
        const unsigned int pr = hits[p];
        const int row = pr >> 16, g = pr & 0xffff;
        const int col = g * 32 + col_l;
        const float4* qp = (const float4*)(queue + (size_t)col * DIM + half * 128);
        const float4* pp = (const float4*)(Pn + (size_t)row * DIM + half * 128);
        float4 sv = {0.f, 0.f, 0.f, 0.f};
        #pragma unroll 8
        for (int j = 0; j < 32; ++j) {
            float4 a = pp[j], b = qp[j];
            sv.x = fmaf(a.x, b.x, sv.x); sv.y = fmaf(a.y, b.y, sv.y);
            sv.z = fmaf(a.z, b.z, sv.z); sv.w = fmaf(a.w, b.w, sv.w);
        }
        float s = (sv.x + sv.y) + (sv.z + sv.w);
        s += __shfl_xor(s, 32, 64);                       // combine k-halves
        unsigned long long best = ((unsigned long long)mono_f32(s) << 32)
                                | (unsigned int)(65535 - col);
        #pragma unroll
        for (int off = 1; off <= 16; off <<= 1) {
            unsigned long long o = __shfl_xor(best, off, 64);
            best = best > o ? best : o;
        }
        if (lane == 0) atomicMax(rowfinal + row, best);
    }
}

// ---------------- k3: S1/S2 sim (blocks 0..511) | FIFO copy B (512..1535) ----------
// Sim: b>>1 = 4-row block (rows of [nn1;nn2]), b&1 = column half.
// Copy B: queue rows [32768, 65024) -> outq rows [33280, 65536), guarded.
__global__ void k3_sim(const unsigned long long* __restrict__ rowfinal,
                       const float* __restrict__ queue,
                       const float* __restrict__ PnT, float* __restrict__ S,
                       float* __restrict__ outq)
{
    const int bid = blockIdx.x;      // 0..1535
    const int tid = threadIdx.x;     // 256

    if (bid >= 512) {
        // ---- FIFO copy part B
        const int b0 = 1024 + (bid - 512);   // 1024..2047
        const int n0 = b0 * 32;              // 32768..65504
        const f32x4* qsrc = (const f32x4*)(queue + (size_t)n0 * DIM);
        f32x4* qdst = (f32x4*)(outq + (size_t)(n0 + BATCH) * DIM);
        #pragma unroll
        for (int it = 0; it < 8; ++it) {
            const int idx = it * 256 + tid;  // 0..2047
            const int r = idx >> 6;
            if (n0 + r < QUEUE - BATCH) qdst[idx] = qsrc[idx];
        }
        return;
    }

    const int b  = bid;              // 0..511
    const int rb = (b >> 1) * 4;     // 0..1020 (rows of [nn1;nn2])
    const int ch = b & 1;            // column half
    const int which = (rb < BATCH) ? 0 : 1;
    const int colbase = which ? 0 : BATCH;    // S1 vs p2 (cols 512..1023), S2 vs p1 (0..511)
    const int col = colbase + ch * 256 + tid;
    __shared__ float nnv[4][DIM];
    #pragma unroll
    for (int j = 0; j < 4; ++j) {
        const int idx = 65535 - (int)(rowfinal[rb + j] & 0xFFFFull);
        nnv[j][tid] = queue[(size_t)idx * DIM + tid];
    }
    __syncthreads();
    float acc[4];
    #pragma unroll
    for (int j = 0; j < 4; ++j) acc[j] = 0.f;
    for (int k4 = 0; k4 < 64; ++k4) {
        float4 nv[4];
        #pragma unroll
        for (int j = 0; j < 4; ++j) nv[j] = ((const float4*)nnv[j])[k4];
        #pragma unroll
        for (int kk = 0; kk < 4; ++kk) {
            const int k = k4 * 4 + kk;
            const float v0 = PnT[(size_t)k * MROWS + col];
            #pragma unroll
            for (int j = 0; j < 4; ++j) {
                const float nj = ((const float*)&nv[j])[kk];
                acc[j] = fmaf(nj, v0, acc[j]);
            }
        }
    }
    const int i0 = rb & (BATCH - 1);
    float* Sout = S + (size_t)which * (BATCH * BATCH);
    #pragma unroll
    for (int j = 0; j < 4; ++j)
        Sout[(size_t)(i0 + j) * BATCH + ch * 256 + tid] = acc[j] * 10.0f;
}

// ---------------- k4: loss ----------------
__global__ void k4_loss(const float* __restrict__ S, float* __restrict__ loss)
{
    const int r = blockIdx.x;        // 0..2047
    const int tid = threadIdx.x;     // 256
    const int grp = r >> 9;
    const int i = r & 511;
    const float* M = S + (size_t)(grp >> 1) * (BATCH * BATCH);
    float x0, x1;
    if (!(grp & 1)) { x0 = M[(size_t)i * BATCH + tid];  x1 = M[(size_t)i * BATCH + tid + 256]; }
    else            { x0 = M[(size_t)tid * BATCH + i];  x1 = M[(size_t)(tid + 256) * BATCH + i]; }
    const float diag = M[(size_t)i * BATCH + i];
    float mx = fmaxf(x0, x1);
    #pragma unroll
    for (int off = 1; off < 64; off <<= 1) mx = fmaxf(mx, __shfl_xor(mx, off, 64));
    __shared__ float redm[4], reds[4];
    if ((tid & 63) == 0) redm[tid >> 6] = mx;
    __syncthreads();
    mx = fmaxf(fmaxf(redm[0], redm[1]), fmaxf(redm[2], redm[3]));
    float e = __expf(x0 - mx) + __expf(x1 - mx);
    #pragma unroll
    for (int off = 1; off < 64; off <<= 1) e += __shfl_xor(e, off, 64);
    if ((tid & 63) == 0) reds[tid >> 6] = e;
    __syncthreads();
    if (tid == 0)
        loss[r] = mx + logf(reds[0] + reds[1] + reds[2] + reds[3]) - diag;
}

// ---------------- launcher ----------------
extern "C" void kernel_launch(void* const* d_in, const int* in_sizes, int n_in,
                              void* d_out, int out_size, void* d_ws, size_t ws_size,
                              hipStream_t stream)
{
    const float* p1    = (const float*)d_in[0];
    const float* p2    = (const float*)d_in[1];
    const float* queue = (const float*)d_in[2];
    float* out  = (float*)d_out;
    float* loss = out;
    float* outq = out + 4 * BATCH;

    // Workspace (~44.5 MB)
    char* w = (char*)d_ws;
    float* cand = (float*)w;                               w += (size_t)NGRP * MROWS * 4;   // 8 MB [g][m]
    unsigned long long* rowfinal = (unsigned long long*)w; w += MROWS * 8;
    unsigned int* rowmaxU = (unsigned int*)w;              w += MROWS * 4;
    float* Pn  = (float*)w;                                w += (size_t)MROWS * DIM * 4;    // 1 MB
    float* PnT = (float*)w;                                w += (size_t)MROWS * DIM * 4;    // 1 MB
    unsigned short* PhiF = (unsigned short*)w;             w += (size_t)MROWS * DIM * 2;    // 0.5 MB
    float* S = (float*)w;                                  w += (size_t)2 * BATCH * BATCH * 4; // 2 MB
    char* Qbf = w;                                         // 32 MB (QUEUE*DIM*2)

    hipLaunchKernelGGL(k01_prep,    dim3(256 + 2048), dim3(256), 0, stream,
                       queue, Qbf, p1, p2, Pn, PnT, PhiF, outq, rowmaxU, rowfinal);
    hipLaunchKernelGGL(k2_mfma,     dim3(1024), dim3(256), 0, stream, PhiF, Qbf, cand, rowmaxU);
    hipLaunchKernelGGL(k2cd,        dim3(1536), dim3(256), 0, stream, cand, rowmaxU, Pn, queue,
                       rowfinal, outq);
    hipLaunchKernelGGL(k3_sim,      dim3(1536), dim3(256), 0, stream, rowfinal, queue, PnT, S, outq);
    hipLaunchKernelGGL(k4_loss,     dim3(4 * BATCH), dim3(256), 0, stream, S, loss);
}